// Round 16
// baseline (135.237 us; speedup 1.0000x reference)
//
#include <hip/hip_runtime.h>
#include <math.h>

// ROI Align, separable two-pass form. B=2, K=128, C=256, IMG=512, OH=OW=16.
// Inputs: bboxess[B,K,4] f32, counts[B,1] i32, p2..p5 f32 pyramids, p6 unused.
// Output: f32 [B,K,C,16,16].
// R6: 77us latency-bound. R7: Occ 49%, 70us -> gather tag-pipe bound.
// R8: LDS-stage region -> ~29us kernel. R9: occupancy 2x -> no change =>
// DS-pipe byte-bound (16 taps x 4B x 16.7M = 1.07 GB LDS reads ~ 20us floor).
// R13: separable: pass1 x-interp X[c][row][16] (global->LDS, 4-tap), pass2
// y-interp = 4 LDS dwords/output (2x ds_read2) -> LDS reads cut 4x to 268 MB.
// Bottom-edge y-clamp: stage one duplicate clamped row so +stride read is
// exactly the ref's clamped row.

constexpr int Bn = 2, Kn = 128, Cn = 256;
constexpr int CSPLIT = 32;           // channel-split blocks per box
constexpr int CCH = Cn / CSPLIT;     // 8 channels per block
constexpr int MAXROWS = 50;          // X row slots (worst ey+1 = 48)
constexpr int XSTR = 17;             // X row stride in dwords (odd -> bank spread)
constexpr int XCH = MAXROWS * XSTR;  // 850 dwords per channel

__device__ __forceinline__ float levelg(int F, int psize) {
  return fmaxf(((float)F + 0.5f) * (float)psize * (1.0f / 512.0f) - 0.5f, 0.0f);
}

__device__ __forceinline__ void to_level(int F, int psize,
                                         int& g0i, int& g1i, float& v) {
  float g = levelg(F, psize);
  float g0 = floorf(g);
  v = g - g0;
  g0i = (int)g0;
  g1i = min(g0i + 1, psize - 1);
}

// x variant: adjacent pair [base, base+1]; edge clamp shifts base to psize-2
// with weights (0,1) -> bit-equivalent to ref's duplicated-tap form.
__device__ __forceinline__ void to_level_pair(int F, int psize,
                                              int& base, float& wlo, float& whi) {
  float g = levelg(F, psize);
  float g0 = floorf(g);
  float v = g - g0;
  int g0i = (int)g0;
  if (g0i >= psize - 1) { base = psize - 2; wlo = 0.0f; whi = 1.0f; }
  else                  { base = g0i;       wlo = 1.0f - v; whi = v; }
}

__device__ __forceinline__ void bin_f(int o, int crop,
                                      int& f0i, int& f1i, float& w1) {
  float s = fmaxf(((float)o + 0.5f) * (float)crop * (1.0f / 16.0f) - 0.5f, 0.0f);
  float f0 = floorf(s);
  w1 = s - f0;
  f0i = (int)f0;
  f1i = min(f0i + 1, crop - 1);
}

__device__ __forceinline__ float2 load_f2(const float* p) {
  float2 v;
  __builtin_memcpy(&v, p, 8);
  return v;
}

__global__ __launch_bounds__(256, 5)
void roialign_kernel(const float* __restrict__ bbox,
                     const int* __restrict__ counts,
                     const float* __restrict__ p2,
                     const float* __restrict__ p3,
                     const float* __restrict__ p4,
                     const float* __restrict__ p5,
                     float* __restrict__ out) {
  __shared__ float X[CCH * XCH];               // 27.2 KB -> 5 blocks/CU

  const int blk = blockIdx.x;
  const int cpart = blk & (CSPLIT - 1);
  const int box = blk >> 5;                    // 0..255 = b*Kn + k
  const int b = box >> 7;
  const int k = box & 127;
  const int t = threadIdx.x;                   // 0..255 = oy*16 + ox
  const int oy = t >> 4, ox = t & 15;

  const long outBase = ((long)box * Cn + cpart * CCH) * 256 + t;

  if (k >= counts[b]) {                        // block-uniform branch
#pragma unroll
    for (int c = 0; c < CCH; ++c) out[outBase + (long)c * 256] = 0.0f;
    return;
  }

  // ---- per-box parameters ----
  const float y1f = bbox[box * 4 + 0], x1f = bbox[box * 4 + 1];
  const float y2f = bbox[box * 4 + 2], x2f = bbox[box * 4 + 3];
  const float area = (y2f - y1f) * (x2f - x1f);
  // lvl = clip(round(0.5*log2(area)-3),2,5)-2 via exact half-even thresholds
  const int lvl = (area > 2048.0f) + (area >= 8192.0f) + (area > 32768.0f);
  const int ph = 128 >> lvl;                   // plane is square
  const int pw = ph;

  const int y1 = min(max((int)rintf(y1f), 0), 511);
  const int x1 = min(max((int)rintf(x1f), 0), 511);
  const int y2 = min(max((int)rintf(y2f), y1 + 1), 512);
  const int x2 = min(max((int)rintf(x2f), x1 + 1), 512);
  const int cropy = y2 - y1, cropx = x2 - x1;

  // ---- this thread's y taps: rows a0,a0+1,b0,b0+1 (clamp via dup row) ----
  int a0, b0;
  float wyr[4];
  {
    int f0i, f1i; float w1;
    bin_f(oy, cropy, f0i, f1i, w1);
    int ga0, ga1, gb0, gb1; float va, vb;
    to_level(y1 + f0i, ph, ga0, ga1, va);
    to_level(y1 + f1i, ph, gb0, gb1, vb);
    a0 = ga0; b0 = gb0;
    wyr[0] = (1.0f - w1) * (1.0f - va);
    wyr[1] = (1.0f - w1) * va;
    wyr[2] = w1 * (1.0f - vb);
    wyr[3] = w1 * vb;
  }

  // ---- this thread's x taps (ox = t & 15, shared by pass 1 and layout) ----
  int bx0, bx1;
  float wxl0, wxh0, wxl1, wxh1;
  {
    int f0i, f1i; float w1;
    bin_f(ox, cropx, f0i, f1i, w1);
    float l0, h0, l1, h1;
    to_level_pair(x1 + f0i, pw, bx0, l0, h0);
    to_level_pair(x1 + f1i, pw, bx1, l1, h1);
    wxl0 = (1.0f - w1) * l0; wxh0 = (1.0f - w1) * h0;
    wxl1 = w1 * l1;          wxh1 = w1 * h1;
  }

  // ---- block-uniform touched row range (monotone in oy) ----
  int y_lo, y_hi;
  {
    int f0a, f1a, f0b, f1b; float wd;
    bin_f(0, cropy, f0a, f1a, wd);
    bin_f(15, cropy, f0b, f1b, wd);
    int g0, g1; float vd;
    to_level(y1 + f0a, ph, g0, g1, vd); y_lo = g0;
    to_level(y1 + f1b, ph, g0, g1, vd); y_hi = g1;
  }
  const int nrows = y_hi - y_lo + 2;           // +1 duplicate clamped row

  const float* Pbase;
  switch (lvl) {
    case 0: Pbase = p2; break;
    case 1: Pbase = p3; break;
    case 2: Pbase = p4; break;
    default: Pbase = p5; break;                // unreachable for this dist
  }
  const int planeStride = ph * pw;
  const float* plane = Pbase + ((long)b * Cn + cpart * CCH) * planeStride;

  if (nrows > MAXROWS) {
    // Safety fallback (unreachable by bound analysis): direct global gathers.
    for (int c = 0; c < CCH; ++c) {
      const float* __restrict__ P = plane + (long)c * planeStride;
      float acc = 0.0f;
      const float2 va0 = load_f2(P + a0 * pw + bx0);
      const float2 va1 = load_f2(P + a0 * pw + bx1);
      const float2 vA0 = load_f2(P + min(a0 + 1, ph - 1) * pw + bx0);
      const float2 vA1 = load_f2(P + min(a0 + 1, ph - 1) * pw + bx1);
      const float2 vb0 = load_f2(P + b0 * pw + bx0);
      const float2 vb1 = load_f2(P + b0 * pw + bx1);
      const float2 vB0 = load_f2(P + min(b0 + 1, ph - 1) * pw + bx0);
      const float2 vB1 = load_f2(P + min(b0 + 1, ph - 1) * pw + bx1);
      acc = fmaf(wyr[0] * wxl0, va0.x, acc); acc = fmaf(wyr[0] * wxh0, va0.y, acc);
      acc = fmaf(wyr[0] * wxl1, va1.x, acc); acc = fmaf(wyr[0] * wxh1, va1.y, acc);
      acc = fmaf(wyr[1] * wxl0, vA0.x, acc); acc = fmaf(wyr[1] * wxh0, vA0.y, acc);
      acc = fmaf(wyr[1] * wxl1, vA1.x, acc); acc = fmaf(wyr[1] * wxh1, vA1.y, acc);
      acc = fmaf(wyr[2] * wxl0, vb0.x, acc); acc = fmaf(wyr[2] * wxh0, vb0.y, acc);
      acc = fmaf(wyr[2] * wxl1, vb1.x, acc); acc = fmaf(wyr[2] * wxh1, vb1.y, acc);
      acc = fmaf(wyr[3] * wxl0, vB0.x, acc); acc = fmaf(wyr[3] * wxh0, vB0.y, acc);
      acc = fmaf(wyr[3] * wxl1, vB1.x, acc); acc = fmaf(wyr[3] * wxh1, vB1.y, acc);
      out[outBase + (long)c * 256] = acc;
    }
    return;
  }

  // ---- pass 1: x-interp rows into X[c][r][ox]; lane = (row-group, ox) ----
  {
    const int rlane = t >> 4;                  // 16 row-lanes x 16 ox-lanes
#pragma unroll 2
    for (int c = 0; c < CCH; ++c) {
      const float* __restrict__ P = plane + (long)c * planeStride;
      float* __restrict__ Xc = X + c * XCH;
      for (int r = rlane; r < nrows; r += 16) {
        const int srow = min(y_lo + r, ph - 1);      // duplicate clamped row
        const float* __restrict__ row = P + srow * pw;
        const float2 v0 = load_f2(row + bx0);
        const float2 v1 = load_f2(row + bx1);
        Xc[r * XSTR + ox] =
            fmaf(wxh1, v1.y, fmaf(wxl1, v1.x, fmaf(wxh0, v0.y, wxl0 * v0.x)));
      }
    }
  }
  __syncthreads();

  // ---- pass 2: y-interp, 4 LDS dwords per output (2x ds_read2_b32) ----
  const int oa = (a0 - y_lo) * XSTR + ox;
  const int ob = (b0 - y_lo) * XSTR + ox;
#pragma unroll 2
  for (int c = 0; c < CCH; ++c) {
    const float* __restrict__ Xc = X + c * XCH;
    float acc = wyr[0] * Xc[oa];
    acc = fmaf(wyr[1], Xc[oa + XSTR], acc);
    acc = fmaf(wyr[2], Xc[ob], acc);
    acc = fmaf(wyr[3], Xc[ob + XSTR], acc);
    out[outBase + (long)c * 256] = acc;
  }
}

extern "C" void kernel_launch(void* const* d_in, const int* in_sizes, int n_in,
                              void* d_out, int out_size, void* d_ws, size_t ws_size,
                              hipStream_t stream) {
  const float* bbox = (const float*)d_in[0];
  const int* counts = (const int*)d_in[1];
  const float* p2 = (const float*)d_in[2];
  const float* p3 = (const float*)d_in[3];
  const float* p4 = (const float*)d_in[4];
  const float* p5 = (const float*)d_in[5];
  float* out = (float*)d_out;

  dim3 grid(Bn * Kn * CSPLIT);
  dim3 block(256);
  roialign_kernel<<<grid, block, 0, stream>>>(bbox, counts, p2, p3, p4, p5, out);
}